// Round 5
// baseline (178.587 us; speedup 1.0000x reference)
//
#include <hip/hip_runtime.h>
#include <hip/hip_bf16.h>
#include <math.h>

#define B_ 32
#define N_ 151
#define DIM_ 512
#define H_ 8
#define D_ 64
#define M_ (B_*N_)        // 4832
#define NPAD 160          // N padded to 16

typedef short bf16x8 __attribute__((ext_vector_type(8)));
typedef float f32x4  __attribute__((ext_vector_type(4)));

static __device__ __forceinline__ short f2bf(float f) {
  union { __hip_bfloat16 h; short s; } u;
  u.h = __float2bfloat16(f);
  return u.s;
}
static __device__ __forceinline__ float bf2f(short s) {
  union { short s; __hip_bfloat16 h; } u;
  u.s = s;
  return __bfloat162float(u.h);
}
// split f32 into hi+lo bf16 pair (v ~= hi + lo)
static __device__ __forceinline__ void split_bf(float v, short& hi, short& lo) {
  hi = f2bf(v);
  lo = f2bf(v - bf2f(hi));
}

// ---------------- PE tables ----------------
__global__ void pe_kernel(const float* __restrict__ angle_enc,
                          const float* __restrict__ cls_dist,
                          const float* __restrict__ cls_angle,
                          float* __restrict__ pe_k, float* __restrict__ pe_v) {
  int bn = blockIdx.x;                 // b*N_ + n
  int b = bn / N_, n = bn - b * N_;
  int d = threadIdx.x;                 // 0..63
  float ek = (n == 0) ? cls_dist[0]  : angle_enc[b*(N_-1) + (n-1)];
  float ev = (n == 0) ? cls_angle[0] : angle_enc[b*(N_-1) + (n-1)];
  float freq = (float)pow(10000.0, (double)(2*(d >> 1)) / 64.0);
  float pk = floorf((ek * 151.0f) / freq);
  float pv = floorf((ev * 151.0f) / freq);
  pe_k[bn*64 + d] = (float)((d & 1) ? cos((double)pk) : sin((double)pk));
  pe_v[bn*64 + d] = (float)((d & 1) ? cos((double)pv) : sin((double)pv));
}

// ---------------- fp32 -> (hi,lo) bf16 convert ----------------
__global__ void cvt_split_kernel(const float* __restrict__ in,
                                 short* __restrict__ oh, short* __restrict__ ol, int n4) {
  int i = blockIdx.x * 256 + threadIdx.x;
  if (i < n4) {
    float4 v = ((const float4*)in)[i];
    short4 h, l;
    split_bf(v.x, h.x, l.x); split_bf(v.y, h.y, l.y);
    split_bf(v.z, h.z, l.z); split_bf(v.w, h.w, l.w);
    ((short4*)oh)[i] = h;
    ((short4*)ol)[i] = l;
  }
}

// ---------------- fp32 (R x C) -> (hi,lo) bf16 transposed (C x R) ----------------
__global__ void transpose_split_kernel(const float* __restrict__ in,
                                       short* __restrict__ oh, short* __restrict__ ol,
                                       int R, int C) {
  __shared__ float tile[32][33];
  int tc = blockIdx.x * 32;
  int tr = blockIdx.y * 32;
  int lx = threadIdx.x & 31, ly = threadIdx.x >> 5;
  #pragma unroll
  for (int dy = 0; dy < 32; dy += 8)
    tile[ly + dy][lx] = in[(tr + ly + dy) * C + tc + lx];
  __syncthreads();
  #pragma unroll
  for (int dy = 0; dy < 32; dy += 8) {
    short h, l;
    split_bf(tile[lx][ly + dy], h, l);
    oh[(tc + ly + dy) * R + tr + lx] = h;
    ol[(tc + ly + dy) * R + tr + lx] = l;
  }
}

// ---------------- compensated bf16 MFMA GEMM: C = (Ah+Al)(Bh+Bl)^T ----------------
// EPI 0: qkv epilogue (Q hi/lo; K' = k + pe_k hi/lo; V' = v + pe_v bf16)
// EPI 1: out epilogue (+bias, write FLOAT32 d_out)
template<int EPI>
__global__ __launch_bounds__(256) void gemm_kernel(
    const short* __restrict__ Ah, const short* __restrict__ Al,
    const short* __restrict__ Bh, const short* __restrict__ Bl,
    const float* __restrict__ pe_k, const float* __restrict__ pe_v,
    short* __restrict__ Qh, short* __restrict__ Ql,
    short* __restrict__ Kh, short* __restrict__ Kl, short* __restrict__ Vb,
    const float* __restrict__ bias, float* __restrict__ Out)
{
  const int K = DIM_;
  __shared__ short Ash[64][40], Asl[64][40];
  __shared__ short Bsh[64][40], Bsl[64][40];
  const int m0 = blockIdx.x * 64;
  const int n0 = blockIdx.y * 64;
  const int t = threadIdx.x;
  const int wave = t >> 6, lane = t & 63;
  const int fr = lane & 15, fq = lane >> 4, fo = fq * 8;
  const int lr = t >> 2, lc = (t & 3) * 8;

  const f32x4 zero = {0.f, 0.f, 0.f, 0.f};
  f32x4 acc[4] = {zero, zero, zero, zero};

  const int gmA = m0 + lr;
  const short* pAh = Ah + (long)gmA * K + lc;
  const short* pAl = Al + (long)gmA * K + lc;
  const short* pBh = Bh + (long)(n0 + lr) * K + lc;
  const short* pBl = Bl + (long)(n0 + lr) * K + lc;

  for (int k0 = 0; k0 < K; k0 += 32) {
    bf16x8 avh = {0,0,0,0,0,0,0,0}, avl = {0,0,0,0,0,0,0,0};
    if (gmA < M_) { avh = *(const bf16x8*)(pAh + k0); avl = *(const bf16x8*)(pAl + k0); }
    *(bf16x8*)(&Ash[lr][lc]) = avh;
    *(bf16x8*)(&Asl[lr][lc]) = avl;
    *(bf16x8*)(&Bsh[lr][lc]) = *(const bf16x8*)(pBh + k0);
    *(bf16x8*)(&Bsl[lr][lc]) = *(const bf16x8*)(pBl + k0);
    __syncthreads();
    bf16x8 ah = *(const bf16x8*)(&Ash[wave*16 + fr][fo]);
    bf16x8 al = *(const bf16x8*)(&Asl[wave*16 + fr][fo]);
    #pragma unroll
    for (int nb = 0; nb < 4; nb++) {
      bf16x8 bh = *(const bf16x8*)(&Bsh[nb*16 + fr][fo]);
      bf16x8 bl = *(const bf16x8*)(&Bsl[nb*16 + fr][fo]);
      acc[nb] = __builtin_amdgcn_mfma_f32_16x16x32_bf16(al, bh, acc[nb], 0, 0, 0);
      acc[nb] = __builtin_amdgcn_mfma_f32_16x16x32_bf16(ah, bl, acc[nb], 0, 0, 0);
      acc[nb] = __builtin_amdgcn_mfma_f32_16x16x32_bf16(ah, bh, acc[nb], 0, 0, 0);
    }
    __syncthreads();
  }

  #pragma unroll
  for (int nb = 0; nb < 4; nb++) {
    #pragma unroll
    for (int r = 0; r < 4; r++) {
      int gm = m0 + wave*16 + fq*4 + r;
      int gn = n0 + nb*16 + fr;
      if (gm >= M_) continue;
      float val = acc[nb][r];
      if (EPI == 0) {
        int b = gm / N_, n = gm - b * N_;
        int sect = gn >> 9;                    // 0=q 1=k 2=v
        int h = (gn >> 6) & 7;
        int d = gn & 63;
        int qi = ((b*H_ + h)*N_ + n)*64 + d;
        if (sect == 0) {
          short hi, lo; split_bf(val, hi, lo);
          Qh[qi] = hi; Ql[qi] = lo;
        } else if (sect == 1) {
          short hi, lo; split_bf(val + pe_k[gm*64 + d], hi, lo);   // K' = k + pe_k
          Kh[qi] = hi; Kl[qi] = lo;
        } else {
          Vb[qi] = f2bf(val + pe_v[gm*64 + d]);                    // V' = v + pe_v
        }
      } else {
        Out[(long)gm*DIM_ + gn] = val + bias[gn];                  // FLOAT32 output
      }
    }
  }
}

// ---------------- fused attention: one block per (b,h) ----------------
__global__ __launch_bounds__(256) void attn_kernel(
    const short* __restrict__ Qh, const short* __restrict__ Ql,
    const short* __restrict__ Kh, const short* __restrict__ Kl,
    const short* __restrict__ Vb, const float* __restrict__ pe_v,
    short* __restrict__ Wh, short* __restrict__ Wl)
{
  __shared__ short Ksh[NPAD][72];
  __shared__ short Ksl[NPAD][72];
  __shared__ short Vt[64][NPAD + 8];
  __shared__ short Ps[4][16][NPAD + 8];

  const int bh = blockIdx.x;
  const int b = bh >> 3, h = bh & 7;
  const int t = threadIdx.x;
  const int wave = t >> 6, lane = t & 63;
  const int fr = lane & 15, fq = lane >> 4, fo = fq * 8;
  const int base = bh * (N_ * 64);

  {
    const int seg = t & 7, r0 = t >> 3;
    for (int r = r0; r < NPAD; r += 32) {
      bf16x8 kh = {0,0,0,0,0,0,0,0}, kl = {0,0,0,0,0,0,0,0}, vv = {0,0,0,0,0,0,0,0};
      if (r < N_) {
        kh = *(const bf16x8*)(Kh + base + r*64 + seg*8);
        kl = *(const bf16x8*)(Kl + base + r*64 + seg*8);
        vv = *(const bf16x8*)(Vb + base + r*64 + seg*8);
      }
      *(bf16x8*)(&Ksh[r][seg*8]) = kh;
      *(bf16x8*)(&Ksl[r][seg*8]) = kl;
      #pragma unroll
      for (int j = 0; j < 8; j++) Vt[seg*8 + j][r] = vv[j];
    }
  }
  __syncthreads();

  const f32x4 zero = {0.f, 0.f, 0.f, 0.f};

  for (int s = wave; s < 10; s += 4) {
    const int q0 = s * 16;
    bf16x8 aq0h = {0,0,0,0,0,0,0,0}, aq1h = {0,0,0,0,0,0,0,0};
    bf16x8 aq0l = {0,0,0,0,0,0,0,0}, aq1l = {0,0,0,0,0,0,0,0};
    if (q0 + fr < N_) {
      const short* qrh = Qh + base + (q0 + fr) * 64;
      const short* qrl = Ql + base + (q0 + fr) * 64;
      aq0h = *(const bf16x8*)(qrh + fo);
      aq1h = *(const bf16x8*)(qrh + 32 + fo);
      aq0l = *(const bf16x8*)(qrl + fo);
      aq1l = *(const bf16x8*)(qrl + 32 + fo);
    }
    f32x4 sf[10];
    #pragma unroll
    for (int kt = 0; kt < 10; kt++) {
      bf16x8 bh0 = *(const bf16x8*)(&Ksh[kt*16 + fr][fo]);
      bf16x8 bh1 = *(const bf16x8*)(&Ksh[kt*16 + fr][32 + fo]);
      bf16x8 bl0 = *(const bf16x8*)(&Ksl[kt*16 + fr][fo]);
      bf16x8 bl1 = *(const bf16x8*)(&Ksl[kt*16 + fr][32 + fo]);
      f32x4 s0 = __builtin_amdgcn_mfma_f32_16x16x32_bf16(aq0l, bh0, zero, 0, 0, 0);
      s0 = __builtin_amdgcn_mfma_f32_16x16x32_bf16(aq0h, bl0, s0, 0, 0, 0);
      s0 = __builtin_amdgcn_mfma_f32_16x16x32_bf16(aq0h, bh0, s0, 0, 0, 0);
      s0 = __builtin_amdgcn_mfma_f32_16x16x32_bf16(aq1l, bh1, s0, 0, 0, 0);
      s0 = __builtin_amdgcn_mfma_f32_16x16x32_bf16(aq1h, bl1, s0, 0, 0, 0);
      sf[kt] = __builtin_amdgcn_mfma_f32_16x16x32_bf16(aq1h, bh1, s0, 0, 0, 0);
    }
    #pragma unroll
    for (int kt = 0; kt < 10; kt++) {
      int col = kt*16 + fr;
      #pragma unroll
      for (int r = 0; r < 4; r++) {
        float v = sf[kt][r] * 0.125f;
        sf[kt][r] = (col < N_) ? v : -1e30f;
      }
    }
    float mx[4], sum[4];
    #pragma unroll
    for (int r = 0; r < 4; r++) {
      float m = sf[0][r];
      #pragma unroll
      for (int kt = 1; kt < 10; kt++) m = fmaxf(m, sf[kt][r]);
      #pragma unroll
      for (int off = 1; off < 16; off <<= 1) m = fmaxf(m, __shfl_xor(m, off));
      mx[r] = m;
    }
    #pragma unroll
    for (int kt = 0; kt < 10; kt++)
      #pragma unroll
      for (int r = 0; r < 4; r++)
        sf[kt][r] = exp2f((sf[kt][r] - mx[r]) * 1.4426950408889634f);
    #pragma unroll
    for (int r = 0; r < 4; r++) {
      float sm = 0.f;
      #pragma unroll
      for (int kt = 0; kt < 10; kt++) sm += sf[kt][r];
      #pragma unroll
      for (int off = 1; off < 16; off <<= 1) sm += __shfl_xor(sm, off);
      sum[r] = sm;
    }
    #pragma unroll
    for (int kt = 0; kt < 10; kt++)
      #pragma unroll
      for (int r = 0; r < 4; r++)
        Ps[wave][fq*4 + r][kt*16 + fr] = f2bf(sf[kt][r]);
    f32x4 o[4] = {zero, zero, zero, zero};
    #pragma unroll
    for (int kc = 0; kc < 5; kc++) {
      bf16x8 pa = *(const bf16x8*)(&Ps[wave][fr][kc*32 + fo]);
      #pragma unroll
      for (int nb = 0; nb < 4; nb++) {
        bf16x8 bv = *(const bf16x8*)(&Vt[nb*16 + fr][kc*32 + fo]);
        o[nb] = __builtin_amdgcn_mfma_f32_16x16x32_bf16(pa, bv, o[nb], 0, 0, 0);
      }
    }
    float inv[4];
    #pragma unroll
    for (int r = 0; r < 4; r++) inv[r] = 1.0f / sum[r];
    #pragma unroll
    for (int nb = 0; nb < 4; nb++) {
      #pragma unroll
      for (int r = 0; r < 4; r++) {
        int n = q0 + fq*4 + r;
        if (n >= N_) continue;
        int d = nb*16 + fr;
        float val = o[nb][r] * inv[r] - pe_v[(b*N_ + n)*64 + d];
        short hi, lo; split_bf(val, hi, lo);
        Wh[(b*N_ + n)*DIM_ + h*64 + d] = hi;
        Wl[(b*N_ + n)*DIM_ + h*64 + d] = lo;
      }
    }
  }
}

extern "C" void kernel_launch(void* const* d_in, const int* in_sizes, int n_in,
                              void* d_out, int out_size, void* d_ws, size_t ws_size,
                              hipStream_t stream) {
  const float* x         = (const float*)d_in[0];
  const float* angle_enc = (const float*)d_in[1];
  const float* W_qkv     = (const float*)d_in[2];
  const float* W_out     = (const float*)d_in[3];
  const float* b_out     = (const float*)d_in[4];
  const float* cls_dist  = (const float*)d_in[5];
  const float* cls_angle = (const float*)d_in[6];

  char* ws = (char*)d_ws;
  size_t off = 0;
  auto carve = [&](size_t bytes) { size_t o = off; off += (bytes + 255) & ~(size_t)255; return o; };
  const size_t MD2 = (size_t)M_ * DIM_ * 2;

  float* pe_k = (float*)(ws + carve((size_t)M_ * 64 * 4));
  float* pe_v = (float*)(ws + carve((size_t)M_ * 64 * 4));
  short* xh   = (short*)(ws + carve(MD2));
  short* xl   = (short*)(ws + carve(MD2));
  short* wqh  = (short*)(ws + carve((size_t)1536 * 512 * 2));
  short* wql  = (short*)(ws + carve((size_t)1536 * 512 * 2));
  short* woh  = (short*)(ws + carve((size_t)512 * 512 * 2));
  short* wol  = (short*)(ws + carve((size_t)512 * 512 * 2));
  short* Qhb  = (short*)(ws + carve(MD2));
  short* Qlb  = (short*)(ws + carve(MD2));
  short* Khb  = (short*)(ws + carve(MD2));
  short* Klb  = (short*)(ws + carve(MD2));
  short* Vb   = (short*)(ws + carve(MD2));
  short* Wh = xh;   // x buffers dead after gemm<0>
  short* Wl = xl;

  pe_kernel<<<M_, 64, 0, stream>>>(angle_enc, cls_dist, cls_angle, pe_k, pe_v);

  int n4 = (M_ * DIM_) / 4;
  cvt_split_kernel<<<(n4 + 255) / 256, 256, 0, stream>>>(x, xh, xl, n4);
  transpose_split_kernel<<<dim3(1536/32, 512/32), 256, 0, stream>>>(W_qkv, wqh, wql, 512, 1536);
  transpose_split_kernel<<<dim3(512/32, 512/32), 256, 0, stream>>>(W_out, woh, wol, 512, 512);

  gemm_kernel<0><<<dim3((M_ + 63)/64, 1536/64), 256, 0, stream>>>(
      xh, xl, wqh, wql, pe_k, pe_v, Qhb, Qlb, Khb, Klb, Vb, nullptr, nullptr);

  attn_kernel<<<B_ * H_, 256, 0, stream>>>(Qhb, Qlb, Khb, Klb, Vb, pe_v, Wh, Wl);

  gemm_kernel<1><<<dim3((M_ + 63)/64, DIM_/64), 256, 0, stream>>>(
      Wh, Wl, woh, wol, nullptr, nullptr,
      nullptr, nullptr, nullptr, nullptr, nullptr, b_out, (float*)d_out);
}

// Round 6
// 172.358 us; speedup vs baseline: 1.0361x; 1.0361x over previous
//
#include <hip/hip_runtime.h>
#include <hip/hip_bf16.h>
#include <math.h>

#define B_ 32
#define N_ 151
#define DIM_ 512
#define H_ 8
#define D_ 64
#define M_ (B_*N_)        // 4832
#define NPAD 160

typedef short bf16x8 __attribute__((ext_vector_type(8)));
typedef float f32x4  __attribute__((ext_vector_type(4)));

static __device__ __forceinline__ short f2bf(float f) {
  union { __hip_bfloat16 h; short s; } u;
  u.h = __float2bfloat16(f);
  return u.s;
}
static __device__ __forceinline__ float bf2f(short s) {
  union { short s; __hip_bfloat16 h; } u;
  u.s = s;
  return __bfloat162float(u.h);
}
static __device__ __forceinline__ void split_bf(float v, short& hi, short& lo) {
  hi = f2bf(v);
  lo = f2bf(v - bf2f(hi));
}
// async global->LDS, 16B per lane; lds dest must be wave-uniform base (+lane*16 implicit)
static __device__ __forceinline__ void gload16(const void* g, void* l) {
  __builtin_amdgcn_global_load_lds(
      (const __attribute__((address_space(1))) unsigned int*)(uintptr_t)g,
      (__attribute__((address_space(3))) unsigned int*)(unsigned int)(uintptr_t)l,
      16, 0, 0);
}

// ---------------- PE tables ----------------
__global__ void pe_kernel(const float* __restrict__ angle_enc,
                          const float* __restrict__ cls_dist,
                          const float* __restrict__ cls_angle,
                          float* __restrict__ pe_k, float* __restrict__ pe_v) {
  int bn = blockIdx.x;
  int b = bn / N_, n = bn - b * N_;
  int d = threadIdx.x;
  float ek = (n == 0) ? cls_dist[0]  : angle_enc[b*(N_-1) + (n-1)];
  float ev = (n == 0) ? cls_angle[0] : angle_enc[b*(N_-1) + (n-1)];
  float freq = (float)pow(10000.0, (double)(2*(d >> 1)) / 64.0);
  float pk = floorf((ek * 151.0f) / freq);
  float pv = floorf((ev * 151.0f) / freq);
  pe_k[bn*64 + d] = (float)((d & 1) ? cos((double)pk) : sin((double)pk));
  pe_v[bn*64 + d] = (float)((d & 1) ? cos((double)pv) : sin((double)pv));
}

// ---------------- fp32 -> (hi,lo) bf16 convert ----------------
__global__ void cvt_split_kernel(const float* __restrict__ in,
                                 short* __restrict__ oh, short* __restrict__ ol, int n4) {
  int i = blockIdx.x * 256 + threadIdx.x;
  if (i < n4) {
    float4 v = ((const float4*)in)[i];
    short4 h, l;
    split_bf(v.x, h.x, l.x); split_bf(v.y, h.y, l.y);
    split_bf(v.z, h.z, l.z); split_bf(v.w, h.w, l.w);
    ((short4*)oh)[i] = h;
    ((short4*)ol)[i] = l;
  }
}

// ---------------- fp32 (R x C) -> (hi,lo) bf16 transposed (C x R) ----------------
__global__ void transpose_split_kernel(const float* __restrict__ in,
                                       short* __restrict__ oh, short* __restrict__ ol,
                                       int R, int C) {
  __shared__ float tile[32][33];
  int tc = blockIdx.x * 32;
  int tr = blockIdx.y * 32;
  int lx = threadIdx.x & 31, ly = threadIdx.x >> 5;
  #pragma unroll
  for (int dy = 0; dy < 32; dy += 8)
    tile[ly + dy][lx] = in[(tr + ly + dy) * C + tc + lx];
  __syncthreads();
  #pragma unroll
  for (int dy = 0; dy < 32; dy += 8) {
    short h, l;
    split_bf(tile[lx][ly + dy], h, l);
    oh[(tc + ly + dy) * R + tr + lx] = h;
    ol[(tc + ly + dy) * R + tr + lx] = l;
  }
}

// ---------------- compensated bf16 MFMA GEMM, m97-style ----------------
// BM=128 x BN_ tile, BK=32, global_load_lds staging, 4 waves.
// EPI 0 (BN_=128): qkv epilogue (Q hi/lo; Kh = bf16(k+pe_k); V' = bf16(v+pe_v))
// EPI 1 (BN_=64):  out epilogue (+bias, write f32 d_out)
template<int EPI, int BN_>
__global__ __launch_bounds__(256, 2) void gemm_kernel(
    const short* __restrict__ Ah, const short* __restrict__ Al,
    const short* __restrict__ Bh, const short* __restrict__ Bl,
    const float* __restrict__ pe_k, const float* __restrict__ pe_v,
    short* __restrict__ Qh, short* __restrict__ Ql,
    short* __restrict__ Kh, short* __restrict__ Vb,
    const float* __restrict__ bias, float* __restrict__ Out)
{
  constexpr int BM = 128;
  constexpr int WM = (BN_ == 128) ? 2 : 4;     // wave grid
  constexpr int WN = (BN_ == 128) ? 2 : 1;
  constexpr int MI = BM / (WM * 16);           // A frags per wave
  constexpr int NI = BN_ / (WN * 16);          // B frags per wave
  __shared__ short Ash[BM][32], Asl[BM][32];
  __shared__ short Bsh[BN_][32], Bsl[BN_][32];

  const int m0 = blockIdx.x * BM;
  const int n0 = blockIdx.y * BN_;
  const int t = threadIdx.x;
  const int wave = t >> 6, lane = t & 63;
  const int fr = lane & 15, fq = lane >> 4, fo = fq * 8;
  const int wr = (WN == 2) ? (wave >> 1) : wave;
  const int wc = (WN == 2) ? (wave & 1) : 0;
  const int lrow = lane >> 2, lcol = (lane & 3) * 8;   // staging: 16 rows x 32 cols per instr

  const f32x4 zero = {0.f, 0.f, 0.f, 0.f};
  f32x4 acc[MI][NI];
  #pragma unroll
  for (int i = 0; i < MI; i++)
    #pragma unroll
    for (int j = 0; j < NI; j++) acc[i][j] = zero;

  auto stage = [&](int k0) {
    #pragma unroll
    for (int cc = 0; cc < 2; cc++) {           // A: 8 chunks of 16 rows
      int c = wave + cc * 4;
      long go = (long)(m0 + c*16 + lrow) * DIM_ + k0 + lcol;
      gload16(Ah + go, &Ash[0][0] + c * 512);
      gload16(Al + go, &Asl[0][0] + c * 512);
    }
    constexpr int BCC = (BN_ / 16) / 4;        // B chunks per wave (2 or 1)
    #pragma unroll
    for (int cc = 0; cc < BCC; cc++) {
      int c = wave + cc * 4;
      long go = (long)(n0 + c*16 + lrow) * DIM_ + k0 + lcol;
      gload16(Bh + go, &Bsh[0][0] + c * 512);
      gload16(Bl + go, &Bsl[0][0] + c * 512);
    }
  };

  stage(0);
  for (int it = 0; it < DIM_ / 32; it++) {
    __syncthreads();                            // drains vmcnt -> LDS ready
    bf16x8 afh[MI], afl[MI], bfh[NI], bfl[NI];
    #pragma unroll
    for (int mi = 0; mi < MI; mi++) {
      int r = wr * (BM / WM) + mi * 16 + fr;
      afh[mi] = *(const bf16x8*)(&Ash[r][fo]);
      afl[mi] = *(const bf16x8*)(&Asl[r][fo]);
    }
    #pragma unroll
    for (int ni = 0; ni < NI; ni++) {
      int r = wc * (BN_ / WN) + ni * 16 + fr;
      bfh[ni] = *(const bf16x8*)(&Bsh[r][fo]);
      bfl[ni] = *(const bf16x8*)(&Bsl[r][fo]);
    }
    #pragma unroll
    for (int mi = 0; mi < MI; mi++)
      #pragma unroll
      for (int ni = 0; ni < NI; ni++) {
        acc[mi][ni] = __builtin_amdgcn_mfma_f32_16x16x32_bf16(afl[mi], bfh[ni], acc[mi][ni], 0, 0, 0);
        acc[mi][ni] = __builtin_amdgcn_mfma_f32_16x16x32_bf16(afh[mi], bfl[ni], acc[mi][ni], 0, 0, 0);
        acc[mi][ni] = __builtin_amdgcn_mfma_f32_16x16x32_bf16(afh[mi], bfh[ni], acc[mi][ni], 0, 0, 0);
      }
    __syncthreads();
    if (it < DIM_ / 32 - 1) stage((it + 1) * 32);
  }

  #pragma unroll
  for (int mi = 0; mi < MI; mi++) {
    #pragma unroll
    for (int ni = 0; ni < NI; ni++) {
      #pragma unroll
      for (int r = 0; r < 4; r++) {
        int gm = m0 + wr * (BM / WM) + mi * 16 + fq * 4 + r;
        int gn = n0 + wc * (BN_ / WN) + ni * 16 + fr;
        if (gm >= M_) continue;
        float val = acc[mi][ni][r];
        if (EPI == 0) {
          int b = gm / N_, n = gm - b * N_;
          int sect = gn >> 9;                  // 0=q 1=k 2=v
          int h = (gn >> 6) & 7;
          int d = gn & 63;
          int qi = ((b*H_ + h)*N_ + n)*64 + d;
          if (sect == 0) {
            short hi, lo; split_bf(val, hi, lo);
            Qh[qi] = hi; Ql[qi] = lo;
          } else if (sect == 1) {
            Kh[qi] = f2bf(val + pe_k[gm*64 + d]);     // K' = k + pe_k (single round)
          } else {
            Vb[qi] = f2bf(val + pe_v[gm*64 + d]);     // V' = v + pe_v
          }
        } else {
          Out[(long)gm*DIM_ + gn] = val + bias[gn];   // f32 output
        }
      }
    }
  }
}

// ---------------- fused attention: grid (256 bh, 3 strip-subsets), 1 strip/wave ----------------
__global__ __launch_bounds__(256, 2) void attn_kernel(
    const short* __restrict__ Qh, const short* __restrict__ Ql,
    const short* __restrict__ Kh,
    const short* __restrict__ Vb, const float* __restrict__ pe_v,
    short* __restrict__ Wh, short* __restrict__ Wl)
{
  __shared__ short Ksh[NPAD][72];          // K' hi  (23 KB)
  __shared__ short Vt[64][NPAD + 8];       // V' transposed [d][n]  (21 KB)
  __shared__ short Ps[4][16][NPAD + 8];    // per-wave P strip       (21 KB)

  const int bh = blockIdx.x;
  const int b = bh >> 3, h = bh & 7;
  const int t = threadIdx.x;
  const int wave = t >> 6, lane = t & 63;
  const int fr = lane & 15, fq = lane >> 4, fo = fq * 8;
  const int base = bh * (N_ * 64);

  {
    const int seg = t & 7, r0 = t >> 3;
    for (int r = r0; r < NPAD; r += 32) {
      bf16x8 kh = {0,0,0,0,0,0,0,0}, vv = {0,0,0,0,0,0,0,0};
      if (r < N_) {
        kh = *(const bf16x8*)(Kh + base + r*64 + seg*8);
        vv = *(const bf16x8*)(Vb + base + r*64 + seg*8);
      }
      *(bf16x8*)(&Ksh[r][seg*8]) = kh;
      #pragma unroll
      for (int j = 0; j < 8; j++) Vt[seg*8 + j][r] = vv[j];
    }
  }
  __syncthreads();

  const int s = blockIdx.y * 4 + wave;       // q-strip id, 0..9 valid
  if (s >= 10) return;
  const int q0 = s * 16;
  const f32x4 zero = {0.f, 0.f, 0.f, 0.f};

  bf16x8 aq0h = {0,0,0,0,0,0,0,0}, aq1h = {0,0,0,0,0,0,0,0};
  bf16x8 aq0l = {0,0,0,0,0,0,0,0}, aq1l = {0,0,0,0,0,0,0,0};
  if (q0 + fr < N_) {
    const short* qrh = Qh + base + (q0 + fr) * 64;
    const short* qrl = Ql + base + (q0 + fr) * 64;
    aq0h = *(const bf16x8*)(qrh + fo);
    aq1h = *(const bf16x8*)(qrh + 32 + fo);
    aq0l = *(const bf16x8*)(qrl + fo);
    aq1l = *(const bf16x8*)(qrl + 32 + fo);
  }
  // S = (Qh+Ql) . K'h   (Q-compensated, 4 MFMA per k-tile)
  f32x4 sf[10];
  #pragma unroll
  for (int kt = 0; kt < 10; kt++) {
    bf16x8 bh0 = *(const bf16x8*)(&Ksh[kt*16 + fr][fo]);
    bf16x8 bh1 = *(const bf16x8*)(&Ksh[kt*16 + fr][32 + fo]);
    f32x4 s0 = __builtin_amdgcn_mfma_f32_16x16x32_bf16(aq0l, bh0, zero, 0, 0, 0);
    s0 = __builtin_amdgcn_mfma_f32_16x16x32_bf16(aq0h, bh0, s0, 0, 0, 0);
    s0 = __builtin_amdgcn_mfma_f32_16x16x32_bf16(aq1l, bh1, s0, 0, 0, 0);
    sf[kt] = __builtin_amdgcn_mfma_f32_16x16x32_bf16(aq1h, bh1, s0, 0, 0, 0);
  }
  #pragma unroll
  for (int kt = 0; kt < 10; kt++) {
    int col = kt*16 + fr;
    #pragma unroll
    for (int r = 0; r < 4; r++) {
      float v = sf[kt][r] * 0.125f;
      sf[kt][r] = (col < N_) ? v : -1e30f;
    }
  }
  float mx[4], sum[4];
  #pragma unroll
  for (int r = 0; r < 4; r++) {
    float m = sf[0][r];
    #pragma unroll
    for (int kt = 1; kt < 10; kt++) m = fmaxf(m, sf[kt][r]);
    #pragma unroll
    for (int off = 1; off < 16; off <<= 1) m = fmaxf(m, __shfl_xor(m, off));
    mx[r] = m;
  }
  #pragma unroll
  for (int kt = 0; kt < 10; kt++)
    #pragma unroll
    for (int r = 0; r < 4; r++)
      sf[kt][r] = exp2f((sf[kt][r] - mx[r]) * 1.4426950408889634f);
  #pragma unroll
  for (int r = 0; r < 4; r++) {
    float sm = 0.f;
    #pragma unroll
    for (int kt = 0; kt < 10; kt++) sm += sf[kt][r];
    #pragma unroll
    for (int off = 1; off < 16; off <<= 1) sm += __shfl_xor(sm, off);
    sum[r] = sm;
  }
  #pragma unroll
  for (int kt = 0; kt < 10; kt++)
    #pragma unroll
    for (int r = 0; r < 4; r++)
      Ps[wave][fq*4 + r][kt*16 + fr] = f2bf(sf[kt][r]);
  f32x4 o[4] = {zero, zero, zero, zero};
  #pragma unroll
  for (int kc = 0; kc < 5; kc++) {
    bf16x8 pa = *(const bf16x8*)(&Ps[wave][fr][kc*32 + fo]);
    #pragma unroll
    for (int nb = 0; nb < 4; nb++) {
      bf16x8 bv = *(const bf16x8*)(&Vt[nb*16 + fr][kc*32 + fo]);
      o[nb] = __builtin_amdgcn_mfma_f32_16x16x32_bf16(pa, bv, o[nb], 0, 0, 0);
    }
  }
  float inv[4];
  #pragma unroll
  for (int r = 0; r < 4; r++) inv[r] = 1.0f / sum[r];
  #pragma unroll
  for (int nb = 0; nb < 4; nb++) {
    #pragma unroll
    for (int r = 0; r < 4; r++) {
      int n = q0 + fq*4 + r;
      if (n >= N_) continue;
      int d = nb*16 + fr;
      float val = o[nb][r] * inv[r] - pe_v[(b*N_ + n)*64 + d];
      short hi, lo; split_bf(val, hi, lo);
      Wh[(b*N_ + n)*DIM_ + h*64 + d] = hi;
      Wl[(b*N_ + n)*DIM_ + h*64 + d] = lo;
    }
  }
}

extern "C" void kernel_launch(void* const* d_in, const int* in_sizes, int n_in,
                              void* d_out, int out_size, void* d_ws, size_t ws_size,
                              hipStream_t stream) {
  const float* x         = (const float*)d_in[0];
  const float* angle_enc = (const float*)d_in[1];
  const float* W_qkv     = (const float*)d_in[2];
  const float* W_out     = (const float*)d_in[3];
  const float* b_out     = (const float*)d_in[4];
  const float* cls_dist  = (const float*)d_in[5];
  const float* cls_angle = (const float*)d_in[6];

  char* ws = (char*)d_ws;
  size_t off = 0;
  auto carve = [&](size_t bytes) { size_t o = off; off += (bytes + 255) & ~(size_t)255; return o; };
  const size_t MD2 = (size_t)M_ * DIM_ * 2;

  float* pe_k = (float*)(ws + carve((size_t)M_ * 64 * 4));
  float* pe_v = (float*)(ws + carve((size_t)M_ * 64 * 4));
  short* xh   = (short*)(ws + carve(MD2));
  short* xl   = (short*)(ws + carve(MD2));
  short* wqh  = (short*)(ws + carve((size_t)1536 * 512 * 2));
  short* wql  = (short*)(ws + carve((size_t)1536 * 512 * 2));
  short* woh  = (short*)(ws + carve((size_t)512 * 512 * 2));
  short* wol  = (short*)(ws + carve((size_t)512 * 512 * 2));
  short* Qhb  = (short*)(ws + carve(MD2));
  short* Qlb  = (short*)(ws + carve(MD2));
  short* Khb  = (short*)(ws + carve(MD2));
  short* Vb   = (short*)(ws + carve(MD2));
  short* Wh = xh;   // x buffers dead after gemm<0>
  short* Wl = xl;

  pe_kernel<<<M_, 64, 0, stream>>>(angle_enc, cls_dist, cls_angle, pe_k, pe_v);

  int n4 = (M_ * DIM_) / 4;
  cvt_split_kernel<<<(n4 + 255) / 256, 256, 0, stream>>>(x, xh, xl, n4);
  transpose_split_kernel<<<dim3(1536/32, 512/32), 256, 0, stream>>>(W_qkv, wqh, wql, 512, 1536);
  transpose_split_kernel<<<dim3(512/32, 512/32), 256, 0, stream>>>(W_out, woh, wol, 512, 512);

  gemm_kernel<0, 128><<<dim3((M_ + 127)/128, 1536/128), 256, 0, stream>>>(
      xh, xl, wqh, wql, pe_k, pe_v, Qhb, Qlb, Khb, Vb, nullptr, nullptr);

  attn_kernel<<<dim3(B_ * H_, 3), 256, 0, stream>>>(Qhb, Qlb, Khb, Vb, pe_v, Wh, Wl);

  gemm_kernel<1, 64><<<dim3((M_ + 127)/128, DIM_/64), 256, 0, stream>>>(
      Wh, Wl, woh, wol, nullptr, nullptr,
      nullptr, nullptr, nullptr, nullptr, b_out, (float*)d_out);
}

// Round 8
// 143.394 us; speedup vs baseline: 1.2454x; 1.2020x over previous
//
#include <hip/hip_runtime.h>
#include <hip/hip_bf16.h>
#include <math.h>

#define B_ 32
#define N_ 151
#define DIM_ 512
#define H_ 8
#define D_ 64
#define M_ (B_*N_)        // 4832
#define NPAD 160

typedef short bf16x8 __attribute__((ext_vector_type(8)));
typedef float f32x4  __attribute__((ext_vector_type(4)));

static __device__ __forceinline__ short f2bf(float f) {
  union { __hip_bfloat16 h; short s; } u;
  u.h = __float2bfloat16(f);
  return u.s;
}
static __device__ __forceinline__ float bf2f(short s) {
  union { short s; __hip_bfloat16 h; } u;
  u.s = s;
  return __bfloat162float(u.h);
}
static __device__ __forceinline__ void split_bf(float v, short& hi, short& lo) {
  hi = f2bf(v);
  lo = f2bf(v - bf2f(hi));
}
// async global->LDS, 16B per lane; lds dest wave-uniform base (+lane*16 implicit)
static __device__ __forceinline__ void gload16(const void* g, void* l) {
  __builtin_amdgcn_global_load_lds(
      (const __attribute__((address_space(1))) unsigned int*)(uintptr_t)g,
      (__attribute__((address_space(3))) unsigned int*)(unsigned int)(uintptr_t)l,
      16, 0, 0);
}

// ---------------- PE tables ----------------
// f64 pow/div/floor (floor-flip-safe, validated); f32 sin/cos (args are small ints)
__global__ void pe_kernel(const float* __restrict__ angle_enc,
                          const float* __restrict__ cls_dist,
                          const float* __restrict__ cls_angle,
                          float* __restrict__ pe_k, float* __restrict__ pe_v) {
  int idx = blockIdx.x * 256 + threadIdx.x;
  if (idx >= M_ * 64) return;
  int bn = idx >> 6, d = idx & 63;
  int b = bn / N_, n = bn - b * N_;
  float ek = (n == 0) ? cls_dist[0]  : angle_enc[b*(N_-1) + (n-1)];
  float ev = (n == 0) ? cls_angle[0] : angle_enc[b*(N_-1) + (n-1)];
  float freq_f = (float)pow(10000.0, (double)(2*(d >> 1)) / 64.0);
  double freq = (double)freq_f;
  float pk = (float)floor(((double)ek * 151.0) / freq);
  float pv = (float)floor(((double)ev * 151.0) / freq);
  pe_k[idx] = (d & 1) ? cosf(pk) : sinf(pk);
  pe_v[idx] = (d & 1) ? cosf(pv) : sinf(pv);
}

// ---------------- fp32 -> bf16 convert ----------------
__global__ void cvt_bf16_kernel(const float* __restrict__ in, short* __restrict__ out, int n4) {
  int i = blockIdx.x * 256 + threadIdx.x;
  if (i < n4) {
    float4 v = ((const float4*)in)[i];
    short4 o;
    o.x = f2bf(v.x); o.y = f2bf(v.y); o.z = f2bf(v.z); o.w = f2bf(v.w);
    ((short4*)out)[i] = o;
  }
}

// ---------------- fp32 (R x C) -> bf16 transposed (C x R) ----------------
__global__ void transpose_bf16_kernel(const float* __restrict__ in, short* __restrict__ out,
                                      int R, int C) {
  __shared__ float tile[32][33];
  int tc = blockIdx.x * 32;
  int tr = blockIdx.y * 32;
  int lx = threadIdx.x & 31, ly = threadIdx.x >> 5;
  #pragma unroll
  for (int dy = 0; dy < 32; dy += 8)
    tile[ly + dy][lx] = in[(tr + ly + dy) * C + tc + lx];
  __syncthreads();
  #pragma unroll
  for (int dy = 0; dy < 32; dy += 8)
    out[(tc + ly + dy) * R + tr + lx] = f2bf(tile[lx][ly + dy]);
}

// ---------------- bf16 MFMA GEMM, double-buffered LDS (T3-minimum 2-phase) ----------------
// C(M x Nt) = A(M x 512) * Bt(Nt x 512)^T
// EPI 0: qkv epilogue (Q hi/lo; Kh = bf16(k+pe_k); Vb = bf16(v+pe_v))
// EPI 1: out epilogue (+bias, f32 d_out)
template<int EPI, int BM, int BN_, int WM, int WN>
__global__ __launch_bounds__(256, 2) void gemm_kernel(
    const short* __restrict__ A, const short* __restrict__ Bt,
    const float* __restrict__ pe_k, const float* __restrict__ pe_v,
    short* __restrict__ Qh, short* __restrict__ Ql,
    short* __restrict__ Kh, short* __restrict__ Vb,
    const float* __restrict__ bias, float* __restrict__ Out)
{
  constexpr int MI = BM / (WM * 16);
  constexpr int NI = BN_ / (WN * 16);
  constexpr int NT = DIM_ / 32;
  __shared__ short Ash[2][BM][32];
  __shared__ short Bsh[2][BN_][32];

  const int m0 = blockIdx.x * BM;
  const int n0 = blockIdx.y * BN_;
  const int t = threadIdx.x;
  const int wave = t >> 6, lane = t & 63;
  const int fr = lane & 15, fq = lane >> 4, fo = fq * 8;
  const int wr = wave / WN, wc = wave % WN;
  const int lrow = lane >> 2, lcol = (lane & 3) * 8;

  const f32x4 zero = {0.f, 0.f, 0.f, 0.f};
  f32x4 acc[MI][NI];
  #pragma unroll
  for (int i = 0; i < MI; i++)
    #pragma unroll
    for (int j = 0; j < NI; j++) acc[i][j] = zero;

  auto stage = [&](int buf, int k0) {
    #pragma unroll
    for (int c = 0; c < BM/16; c += 4) {
      int cc = c + wave;
      gload16(A + (long)(m0 + cc*16 + lrow) * DIM_ + k0 + lcol,
              &Ash[buf][0][0] + cc * 512);
    }
    #pragma unroll
    for (int c = 0; c < BN_/16; c += 4) {
      int cc = c + wave;
      gload16(Bt + (long)(n0 + cc*16 + lrow) * DIM_ + k0 + lcol,
              &Bsh[buf][0][0] + cc * 512);
    }
  };

  // prologue: fill buf 0, drain, barrier
  stage(0, 0);
  asm volatile("s_waitcnt vmcnt(0)" ::: "memory");
  __syncthreads();

  int cur = 0;
  for (int it = 0; it < NT; ++it) {
    // issue next-tile loads into the OTHER buffer (no one reads it this iter)
    if (it + 1 < NT) stage(cur ^ 1, (it + 1) * 32);

    bf16x8 af[MI], bf[NI];
    #pragma unroll
    for (int mi = 0; mi < MI; mi++)
      af[mi] = *(const bf16x8*)(&Ash[cur][wr * (BM/WM) + mi*16 + fr][fo]);
    #pragma unroll
    for (int ni = 0; ni < NI; ni++)
      bf[ni] = *(const bf16x8*)(&Bsh[cur][wc * (BN_/WN) + ni*16 + fr][fo]);
    #pragma unroll
    for (int mi = 0; mi < MI; mi++)
      #pragma unroll
      for (int ni = 0; ni < NI; ni++)
        acc[mi][ni] = __builtin_amdgcn_mfma_f32_16x16x32_bf16(af[mi], bf[ni], acc[mi][ni], 0, 0, 0);

    // drain prefetch, then barrier: next buffer fully written, everyone done reading cur
    asm volatile("s_waitcnt vmcnt(0)" ::: "memory");
    __syncthreads();
    cur ^= 1;
  }

  #pragma unroll
  for (int mi = 0; mi < MI; mi++) {
    #pragma unroll
    for (int ni = 0; ni < NI; ni++) {
      #pragma unroll
      for (int r = 0; r < 4; r++) {
        int gm = m0 + wr * (BM/WM) + mi*16 + fq*4 + r;
        int gn = n0 + wc * (BN_/WN) + ni*16 + fr;
        if (gm >= M_) continue;
        float val = acc[mi][ni][r];
        if (EPI == 0) {
          int b = gm / N_, n = gm - b * N_;
          int sect = gn >> 9;                  // 0=q 1=k 2=v
          int h = (gn >> 6) & 7;
          int d = gn & 63;
          int qi = ((b*H_ + h)*N_ + n)*64 + d;
          if (sect == 0) {
            short hi, lo; split_bf(val, hi, lo);
            Qh[qi] = hi; Ql[qi] = lo;
          } else if (sect == 1) {
            Kh[qi] = f2bf(val + pe_k[gm*64 + d]);     // K' = k + pe_k
          } else {
            Vb[qi] = f2bf(val + pe_v[gm*64 + d]);     // V' = v + pe_v
          }
        } else {
          Out[(long)gm*DIM_ + gn] = val + bias[gn];   // f32 output
        }
      }
    }
  }
}

// ---------------- fused attention: grid (256 bh, 3), 1 q-strip per wave ----------------
__global__ __launch_bounds__(256, 2) void attn_kernel(
    const short* __restrict__ Qh, const short* __restrict__ Ql,
    const short* __restrict__ Kh,
    const short* __restrict__ Vb, const float* __restrict__ pe_v,
    short* __restrict__ Wh)
{
  __shared__ short Ksh[NPAD][72];          // K' hi  (23 KB)
  __shared__ short Vt[64][NPAD + 8];       // V' transposed [d][n]  (21 KB)
  __shared__ short Ps[4][16][NPAD + 8];    // per-wave P strip       (21 KB)

  const int bh = blockIdx.x;
  const int b = bh >> 3, h = bh & 7;
  const int t = threadIdx.x;
  const int wave = t >> 6, lane = t & 63;
  const int fr = lane & 15, fq = lane >> 4, fo = fq * 8;
  const int base = bh * (N_ * 64);

  {
    const int seg = t & 7, r0 = t >> 3;
    for (int r = r0; r < NPAD; r += 32) {
      bf16x8 kh = {0,0,0,0,0,0,0,0}, vv = {0,0,0,0,0,0,0,0};
      if (r < N_) {
        kh = *(const bf16x8*)(Kh + base + r*64 + seg*8);
        vv = *(const bf16x8*)(Vb + base + r*64 + seg*8);
      }
      *(bf16x8*)(&Ksh[r][seg*8]) = kh;
      #pragma unroll
      for (int j = 0; j < 8; j++) Vt[seg*8 + j][r] = vv[j];
    }
  }
  __syncthreads();

  const int s = blockIdx.y * 4 + wave;       // q-strip id, 0..9 valid
  if (s < 10) {
    const int q0 = s * 16;
    const f32x4 zero = {0.f, 0.f, 0.f, 0.f};

    bf16x8 aq0h = {0,0,0,0,0,0,0,0}, aq1h = {0,0,0,0,0,0,0,0};
    bf16x8 aq0l = {0,0,0,0,0,0,0,0}, aq1l = {0,0,0,0,0,0,0,0};
    if (q0 + fr < N_) {
      const short* qrh = Qh + base + (q0 + fr) * 64;
      const short* qrl = Ql + base + (q0 + fr) * 64;
      aq0h = *(const bf16x8*)(qrh + fo);
      aq1h = *(const bf16x8*)(qrh + 32 + fo);
      aq0l = *(const bf16x8*)(qrl + fo);
      aq1l = *(const bf16x8*)(qrl + 32 + fo);
    }
    // S = (Qh+Ql) . K'h
    f32x4 sf[10];
    #pragma unroll
    for (int kt = 0; kt < 10; kt++) {
      bf16x8 bh0 = *(const bf16x8*)(&Ksh[kt*16 + fr][fo]);
      bf16x8 bh1 = *(const bf16x8*)(&Ksh[kt*16 + fr][32 + fo]);
      f32x4 s0 = __builtin_amdgcn_mfma_f32_16x16x32_bf16(aq0l, bh0, zero, 0, 0, 0);
      s0 = __builtin_amdgcn_mfma_f32_16x16x32_bf16(aq0h, bh0, s0, 0, 0, 0);
      s0 = __builtin_amdgcn_mfma_f32_16x16x32_bf16(aq1l, bh1, s0, 0, 0, 0);
      sf[kt] = __builtin_amdgcn_mfma_f32_16x16x32_bf16(aq1h, bh1, s0, 0, 0, 0);
    }
    #pragma unroll
    for (int kt = 0; kt < 10; kt++) {
      int col = kt*16 + fr;
      #pragma unroll
      for (int r = 0; r < 4; r++) {
        float v = sf[kt][r] * 0.125f;
        sf[kt][r] = (col < N_) ? v : -1e30f;
      }
    }
    float mx[4], sum[4];
    #pragma unroll
    for (int r = 0; r < 4; r++) {
      float m = sf[0][r];
      #pragma unroll
      for (int kt = 1; kt < 10; kt++) m = fmaxf(m, sf[kt][r]);
      #pragma unroll
      for (int off = 1; off < 16; off <<= 1) m = fmaxf(m, __shfl_xor(m, off));
      mx[r] = m;
    }
    #pragma unroll
    for (int kt = 0; kt < 10; kt++)
      #pragma unroll
      for (int r = 0; r < 4; r++)
        sf[kt][r] = exp2f((sf[kt][r] - mx[r]) * 1.4426950408889634f);
    #pragma unroll
    for (int r = 0; r < 4; r++) {
      float sm = 0.f;
      #pragma unroll
      for (int kt = 0; kt < 10; kt++) sm += sf[kt][r];
      #pragma unroll
      for (int off = 1; off < 16; off <<= 1) sm += __shfl_xor(sm, off);
      sum[r] = sm;
    }
    #pragma unroll
    for (int kt = 0; kt < 10; kt++)
      #pragma unroll
      for (int r = 0; r < 4; r++)
        Ps[wave][fq*4 + r][kt*16 + fr] = f2bf(sf[kt][r]);
    f32x4 o[4] = {zero, zero, zero, zero};
    #pragma unroll
    for (int kc = 0; kc < 5; kc++) {
      bf16x8 pa = *(const bf16x8*)(&Ps[wave][fr][kc*32 + fo]);
      #pragma unroll
      for (int nb = 0; nb < 4; nb++) {
        bf16x8 bv = *(const bf16x8*)(&Vt[nb*16 + fr][kc*32 + fo]);
        o[nb] = __builtin_amdgcn_mfma_f32_16x16x32_bf16(pa, bv, o[nb], 0, 0, 0);
      }
    }
    float inv[4];
    #pragma unroll
    for (int r = 0; r < 4; r++) inv[r] = 1.0f / sum[r];
    #pragma unroll
    for (int nb = 0; nb < 4; nb++) {
      #pragma unroll
      for (int r = 0; r < 4; r++) {
        int n = q0 + fq*4 + r;
        if (n < N_) {
          int d = nb*16 + fr;
          float val = o[nb][r] * inv[r] - pe_v[(b*N_ + n)*64 + d];
          Wh[(b*N_ + n)*DIM_ + h*64 + d] = f2bf(val);
        }
      }
    }
  }
}

extern "C" void kernel_launch(void* const* d_in, const int* in_sizes, int n_in,
                              void* d_out, int out_size, void* d_ws, size_t ws_size,
                              hipStream_t stream) {
  const float* x         = (const float*)d_in[0];
  const float* angle_enc = (const float*)d_in[1];
  const float* W_qkv     = (const float*)d_in[2];
  const float* W_out     = (const float*)d_in[3];
  const float* b_out     = (const float*)d_in[4];
  const float* cls_dist  = (const float*)d_in[5];
  const float* cls_angle = (const float*)d_in[6];

  char* ws = (char*)d_ws;
  size_t off = 0;
  auto carve = [&](size_t bytes) { size_t o = off; off += (bytes + 255) & ~(size_t)255; return o; };
  const size_t MD2 = (size_t)M_ * DIM_ * 2;

  float* pe_k = (float*)(ws + carve((size_t)M_ * 64 * 4));
  float* pe_v = (float*)(ws + carve((size_t)M_ * 64 * 4));
  short* xb   = (short*)(ws + carve(MD2));
  short* wqT  = (short*)(ws + carve((size_t)1536 * 512 * 2));
  short* woT  = (short*)(ws + carve((size_t)512 * 512 * 2));
  short* Qhb  = (short*)(ws + carve(MD2));
  short* Qlb  = (short*)(ws + carve(MD2));
  short* Khb  = (short*)(ws + carve(MD2));
  short* Vb   = (short*)(ws + carve(MD2));
  short* Wh   = xb;   // xb dead after gemm<0>

  pe_kernel<<<(M_*64 + 255)/256, 256, 0, stream>>>(angle_enc, cls_dist, cls_angle, pe_k, pe_v);

  int n4 = (M_ * DIM_) / 4;
  cvt_bf16_kernel<<<(n4 + 255) / 256, 256, 0, stream>>>(x, xb, n4);
  transpose_bf16_kernel<<<dim3(1536/32, 512/32), 256, 0, stream>>>(W_qkv, wqT, 512, 1536);
  transpose_bf16_kernel<<<dim3(512/32, 512/32), 256, 0, stream>>>(W_out, woT, 512, 512);

  gemm_kernel<0, 64, 128, 1, 4><<<dim3((M_ + 63)/64, 1536/128), 256, 0, stream>>>(
      xb, wqT, pe_k, pe_v, Qhb, Qlb, Khb, Vb, nullptr, nullptr);

  attn_kernel<<<dim3(B_ * H_, 3), 256, 0, stream>>>(Qhb, Qlb, Khb, Vb, pe_v, Wh);

  gemm_kernel<1, 64, 64, 2, 2><<<dim3((M_ + 63)/64, DIM_/64), 256, 0, stream>>>(
      Wh, woT, nullptr, nullptr, nullptr, nullptr, nullptr, nullptr,
      b_out, (float*)d_out);
}

// Round 9
// 135.403 us; speedup vs baseline: 1.3189x; 1.0590x over previous
//
#include <hip/hip_runtime.h>
#include <hip/hip_bf16.h>
#include <math.h>

#define B_ 32
#define N_ 151
#define DIM_ 512
#define H_ 8
#define D_ 64
#define M_ (B_*N_)        // 4832
#define NPAD 160

typedef short bf16x8 __attribute__((ext_vector_type(8)));
typedef float f32x4  __attribute__((ext_vector_type(4)));

static __device__ __forceinline__ short f2bf(float f) {
  union { __hip_bfloat16 h; short s; } u;
  u.h = __float2bfloat16(f);
  return u.s;
}
// async global->LDS, 16B per lane; lds dest wave-uniform base (+lane*16 implicit)
static __device__ __forceinline__ void gload16(const void* g, void* l) {
  __builtin_amdgcn_global_load_lds(
      (const __attribute__((address_space(1))) unsigned int*)(uintptr_t)g,
      (__attribute__((address_space(3))) unsigned int*)(unsigned int)(uintptr_t)l,
      16, 0, 0);
}

// ---------------- fused prep: W transposes + PE tables + x cvt (1024 blocks) ----------------
__global__ __launch_bounds__(256) void prep_kernel(
    const float* __restrict__ x, const float* __restrict__ W_qkv,
    const float* __restrict__ W_out, const float* __restrict__ angle_enc,
    const float* __restrict__ cls_dist, const float* __restrict__ cls_angle,
    short* __restrict__ xb, short* __restrict__ wqT, short* __restrict__ woT,
    float* __restrict__ pe_k, float* __restrict__ pe_v)
{
  __shared__ float smf[32*33];
  const int bx = blockIdx.x;
  const int t = threadIdx.x;
  const int lx = t & 31, ly = t >> 5;

  // --- transpose section: blocks 0..767 -> W_qkv (512x1536); 768..1023 -> W_out (512x512)
  {
    const float* in; short* out; int R, C, tc, tr;
    if (bx < 768) { in = W_qkv; out = wqT; R = 512; C = 1536; tc = (bx % 48) * 32; tr = (bx / 48) * 32; }
    else          { in = W_out; out = woT; R = 512; C = 512;  tc = ((bx - 768) % 16) * 32; tr = ((bx - 768) / 16) * 32; }
    float (*tile)[33] = (float(*)[33])smf;
    #pragma unroll
    for (int dy = 0; dy < 32; dy += 8)
      tile[ly + dy][lx] = in[(tr + ly + dy) * C + tc + lx];
    __syncthreads();
    #pragma unroll
    for (int dy = 0; dy < 32; dy += 8)
      out[(tc + ly + dy) * R + tr + lx] = f2bf(tile[lx][ly + dy]);
  }
  __syncthreads();

  // --- freq table (32 values, f64 pow once per block)
  if (t < 32) smf[t] = (float)pow(10000.0, (double)t / 32.0);
  __syncthreads();

  // --- PE tables, grid-stride
  for (int idx = bx * 256 + t; idx < M_ * 64; idx += 1024 * 256) {
    int bn = idx >> 6, d = idx & 63;
    int b = bn / N_, n = bn - b * N_;
    float ek = (n == 0) ? cls_dist[0]  : angle_enc[b*(N_-1) + (n-1)];
    float ev = (n == 0) ? cls_angle[0] : angle_enc[b*(N_-1) + (n-1)];
    double freq = (double)smf[(d >> 1)];
    float pk = (float)floor(((double)ek * 151.0) / freq);
    float pv = (float)floor(((double)ev * 151.0) / freq);
    pe_k[idx] = (d & 1) ? cosf(pk) : sinf(pk);
    pe_v[idx] = (d & 1) ? cosf(pv) : sinf(pv);
  }

  // --- x -> bf16, grid-stride over float4s
  const int n4 = (M_ * DIM_) / 4;
  for (int i = bx * 256 + t; i < n4; i += 1024 * 256) {
    float4 v = ((const float4*)x)[i];
    short4 o;
    o.x = f2bf(v.x); o.y = f2bf(v.y); o.z = f2bf(v.z); o.w = f2bf(v.w);
    ((short4*)xb)[i] = o;
  }
}

// ---------------- bf16 MFMA GEMM, dbuf BK=64, XOR-swizzled LDS ----------------
// C(M x Nt) = A(M x 512) * Bt(Nt x 512)^T
// EPI 0: qkv epilogue (Q bf16; Kh = bf16(k+pe_k); Vt_g = bf16(v+pe_v) TRANSPOSED [bh][d][n160])
// EPI 1: out epilogue (+bias, f32 d_out)
template<int EPI, int BM, int BN_, int WM, int WN>
__global__ __launch_bounds__(256, 3) void gemm_kernel(
    const short* __restrict__ A, const short* __restrict__ Bt,
    const float* __restrict__ pe_k, const float* __restrict__ pe_v,
    short* __restrict__ Qb, short* __restrict__ Kh, short* __restrict__ Vtg,
    const float* __restrict__ bias, float* __restrict__ Out)
{
  constexpr int MI = BM / (WM * 16);
  constexpr int NI = BN_ / (WN * 16);
  constexpr int NT = DIM_ / 64;
  __shared__ short Ash[2][BM][64];
  __shared__ short Bsh[2][BN_][64];

  const int m0 = blockIdx.x * BM;
  const int n0 = blockIdx.y * BN_;
  const int t = threadIdx.x;
  const int wave = t >> 6, lane = t & 63;
  const int fr = lane & 15, fq = lane >> 4;
  const int wr = wave / WN, wc = wave % WN;
  // staging: chunk of 8 rows, lane covers row c*8+(lane>>3), 16B at swizzled col
  const int srow = lane >> 3;                       // 0..7
  const int scol = ((lane & 7) ^ srow) << 3;        // pre-swizzled source col (shorts)

  const f32x4 zero = {0.f, 0.f, 0.f, 0.f};
  f32x4 acc[MI][NI];
  #pragma unroll
  for (int i = 0; i < MI; i++)
    #pragma unroll
    for (int j = 0; j < NI; j++) acc[i][j] = zero;

  auto stage = [&](int buf, int k0) {
    #pragma unroll
    for (int c = wave; c < BM/8; c += 4)
      gload16(A + (long)(m0 + c*8 + srow) * DIM_ + k0 + scol, &Ash[buf][c*8][0]);
    #pragma unroll
    for (int c = wave; c < BN_/8; c += 4)
      gload16(Bt + (long)(n0 + c*8 + srow) * DIM_ + k0 + scol, &Bsh[buf][c*8][0]);
  };

  stage(0, 0);
  asm volatile("s_waitcnt vmcnt(0)" ::: "memory");
  __syncthreads();

  int cur = 0;
  for (int it = 0; it < NT; ++it) {
    if (it + 1 < NT) stage(cur ^ 1, (it + 1) * 64);

    #pragma unroll
    for (int kk = 0; kk < 2; kk++) {
      const int rc = (kk*32 + fq*8) ^ ((fr & 7) << 3);   // swizzled read col (shorts)
      bf16x8 af[MI], bf[NI];
      #pragma unroll
      for (int mi = 0; mi < MI; mi++)
        af[mi] = *(const bf16x8*)(&Ash[cur][wr * (BM/WM) + mi*16 + fr][rc]);
      #pragma unroll
      for (int ni = 0; ni < NI; ni++)
        bf[ni] = *(const bf16x8*)(&Bsh[cur][wc * (BN_/WN) + ni*16 + fr][rc]);
      #pragma unroll
      for (int mi = 0; mi < MI; mi++)
        #pragma unroll
        for (int ni = 0; ni < NI; ni++)
          acc[mi][ni] = __builtin_amdgcn_mfma_f32_16x16x32_bf16(af[mi], bf[ni], acc[mi][ni], 0, 0, 0);
    }

    asm volatile("s_waitcnt vmcnt(0)" ::: "memory");
    __syncthreads();
    cur ^= 1;
  }

  const int fo = fq * 8;
  (void)fo;
  #pragma unroll
  for (int mi = 0; mi < MI; mi++) {
    #pragma unroll
    for (int ni = 0; ni < NI; ni++) {
      #pragma unroll
      for (int r = 0; r < 4; r++) {
        int gm = m0 + wr * (BM/WM) + mi*16 + fq*4 + r;
        int gn = n0 + wc * (BN_/WN) + ni*16 + fr;
        if (gm >= M_) continue;
        float val = acc[mi][ni][r];
        if (EPI == 0) {
          int b = gm / N_, n = gm - b * N_;
          int sect = gn >> 9;                  // 0=q 1=k 2=v
          int h = (gn >> 6) & 7;
          int d = gn & 63;
          int bh = b*H_ + h;
          if (sect == 0) {
            Qb[(bh*N_ + n)*64 + d] = f2bf(val);
          } else if (sect == 1) {
            Kh[(bh*N_ + n)*64 + d] = f2bf(val + pe_k[gm*64 + d]);   // K' = k + pe_k
          } else {
            Vtg[((long)bh*64 + d)*160 + n] = f2bf(val + pe_v[gm*64 + d]); // V'^T
          }
        } else {
          Out[(long)gm*DIM_ + gn] = val + bias[gn];   // f32 output
        }
      }
    }
  }
}

// ---------------- fused attention: grid (256 bh, 3), 1 q-strip per wave ----------------
__global__ __launch_bounds__(256, 2) void attn_kernel(
    const short* __restrict__ Qb, const short* __restrict__ Kh,
    const short* __restrict__ Vtg, const float* __restrict__ pe_v,
    short* __restrict__ Wh)
{
  __shared__ short Ksh[NPAD][72];          // K' (23 KB)
  __shared__ short Vt[64][NPAD + 8];       // V'^T [d][n]  (21.5 KB)
  __shared__ short Ps[4][16][NPAD + 8];    // per-wave P strip (21.5 KB)

  const int bh = blockIdx.x;
  const int b = bh >> 3, h = bh & 7;
  const int t = threadIdx.x;
  const int wave = t >> 6, lane = t & 63;
  const int fr = lane & 15, fq = lane >> 4, fo = fq * 8;
  const int base = bh * (N_ * 64);

  {
    // K rows: vector loads, zero-pad rows >= N_
    const int seg = t & 7, r0 = t >> 3;
    for (int r = r0; r < NPAD; r += 32) {
      bf16x8 kh = {0,0,0,0,0,0,0,0};
      if (r < N_) kh = *(const bf16x8*)(Kh + base + r*64 + seg*8);
      *(bf16x8*)(&Ksh[r][seg*8]) = kh;
    }
    // V^T rows: pure vector loads from pre-transposed global
    const int vrow = t >> 2;
    const long vbase = ((long)bh * 64 + vrow) * 160;
    #pragma unroll
    for (int c = 0; c < 5; c++) {
      int col = (t & 3) * 8 + c * 32;
      *(bf16x8*)(&Vt[vrow][col]) = *(const bf16x8*)(Vtg + vbase + col);
    }
  }
  __syncthreads();

  const int s = blockIdx.y * 4 + wave;       // q-strip id, 0..9 valid
  if (s < 10) {
    const int q0 = s * 16;
    const f32x4 zero = {0.f, 0.f, 0.f, 0.f};

    bf16x8 aq0 = {0,0,0,0,0,0,0,0}, aq1 = {0,0,0,0,0,0,0,0};
    if (q0 + fr < N_) {
      const short* qr = Qb + base + (q0 + fr) * 64;
      aq0 = *(const bf16x8*)(qr + fo);
      aq1 = *(const bf16x8*)(qr + 32 + fo);
    }
    f32x4 sf[10];
    #pragma unroll
    for (int kt = 0; kt < 10; kt++) {
      bf16x8 bh0 = *(const bf16x8*)(&Ksh[kt*16 + fr][fo]);
      bf16x8 bh1 = *(const bf16x8*)(&Ksh[kt*16 + fr][32 + fo]);
      f32x4 s0 = __builtin_amdgcn_mfma_f32_16x16x32_bf16(aq0, bh0, zero, 0, 0, 0);
      sf[kt]   = __builtin_amdgcn_mfma_f32_16x16x32_bf16(aq1, bh1, s0, 0, 0, 0);
    }
    #pragma unroll
    for (int kt = 0; kt < 10; kt++) {
      int col = kt*16 + fr;
      #pragma unroll
      for (int r = 0; r < 4; r++) {
        float v = sf[kt][r] * 0.125f;
        sf[kt][r] = (col < N_) ? v : -1e30f;
      }
    }
    float mx[4], sum[4];
    #pragma unroll
    for (int r = 0; r < 4; r++) {
      float m = sf[0][r];
      #pragma unroll
      for (int kt = 1; kt < 10; kt++) m = fmaxf(m, sf[kt][r]);
      #pragma unroll
      for (int off = 1; off < 16; off <<= 1) m = fmaxf(m, __shfl_xor(m, off));
      mx[r] = m;
    }
    #pragma unroll
    for (int kt = 0; kt < 10; kt++)
      #pragma unroll
      for (int r = 0; r < 4; r++)
        sf[kt][r] = exp2f((sf[kt][r] - mx[r]) * 1.4426950408889634f);
    #pragma unroll
    for (int r = 0; r < 4; r++) {
      float sm = 0.f;
      #pragma unroll
      for (int kt = 0; kt < 10; kt++) sm += sf[kt][r];
      #pragma unroll
      for (int off = 1; off < 16; off <<= 1) sm += __shfl_xor(sm, off);
      sum[r] = sm;
    }
    #pragma unroll
    for (int kt = 0; kt < 10; kt++)
      #pragma unroll
      for (int r = 0; r < 4; r++)
        Ps[wave][fq*4 + r][kt*16 + fr] = f2bf(sf[kt][r]);
    f32x4 o[4] = {zero, zero, zero, zero};
    #pragma unroll
    for (int kc = 0; kc < 5; kc++) {
      bf16x8 pa = *(const bf16x8*)(&Ps[wave][fr][kc*32 + fo]);
      #pragma unroll
      for (int nb = 0; nb < 4; nb++) {
        bf16x8 bv = *(const bf16x8*)(&Vt[nb*16 + fr][kc*32 + fo]);
        o[nb] = __builtin_amdgcn_mfma_f32_16x16x32_bf16(pa, bv, o[nb], 0, 0, 0);
      }
    }
    float inv[4];
    #pragma unroll
    for (int r = 0; r < 4; r++) inv[r] = 1.0f / sum[r];
    #pragma unroll
    for (int nb = 0; nb < 4; nb++) {
      #pragma unroll
      for (int r = 0; r < 4; r++) {
        int n = q0 + fq*4 + r;
        if (n < N_) {
          int d = nb*16 + fr;
          float val = o[nb][r] * inv[r] - pe_v[(b*N_ + n)*64 + d];
          Wh[(b*N_ + n)*DIM_ + h*64 + d] = f2bf(val);
        }
      }
    }
  }
}

extern "C" void kernel_launch(void* const* d_in, const int* in_sizes, int n_in,
                              void* d_out, int out_size, void* d_ws, size_t ws_size,
                              hipStream_t stream) {
  const float* x         = (const float*)d_in[0];
  const float* angle_enc = (const float*)d_in[1];
  const float* W_qkv     = (const float*)d_in[2];
  const float* W_out     = (const float*)d_in[3];
  const float* b_out     = (const float*)d_in[4];
  const float* cls_dist  = (const float*)d_in[5];
  const float* cls_angle = (const float*)d_in[6];

  char* ws = (char*)d_ws;
  size_t off = 0;
  auto carve = [&](size_t bytes) { size_t o = off; off += (bytes + 255) & ~(size_t)255; return o; };
  const size_t MD2 = (size_t)M_ * DIM_ * 2;

  float* pe_k = (float*)(ws + carve((size_t)M_ * 64 * 4));
  float* pe_v = (float*)(ws + carve((size_t)M_ * 64 * 4));
  short* xb   = (short*)(ws + carve(MD2));
  short* wqT  = (short*)(ws + carve((size_t)1536 * 512 * 2));
  short* woT  = (short*)(ws + carve((size_t)512 * 512 * 2));
  short* Qb   = (short*)(ws + carve(MD2));
  short* Khb  = (short*)(ws + carve(MD2));
  short* Vtg  = (short*)(ws + carve((size_t)B_ * H_ * 64 * 160 * 2));
  short* Wh   = xb;   // xb dead after gemm<0>

  prep_kernel<<<1024, 256, 0, stream>>>(x, W_qkv, W_out, angle_enc, cls_dist, cls_angle,
                                        xb, wqT, woT, pe_k, pe_v);

  gemm_kernel<0, 64, 128, 1, 4><<<dim3((M_ + 63)/64, 1536/128), 256, 0, stream>>>(
      xb, wqT, pe_k, pe_v, Qb, Khb, Vtg, nullptr, nullptr);

  attn_kernel<<<dim3(B_ * H_, 3), 256, 0, stream>>>(Qb, Khb, Vtg, pe_v, Wh);

  gemm_kernel<1, 64, 64, 2, 2><<<dim3((M_ + 63)/64, DIM_/64), 256, 0, stream>>>(
      Wh, woT, nullptr, nullptr, nullptr, nullptr, nullptr,
      b_out, (float*)d_out);
}

// Round 10
// 132.766 us; speedup vs baseline: 1.3451x; 1.0199x over previous
//
#include <hip/hip_runtime.h>
#include <hip/hip_bf16.h>
#include <math.h>

#define B_ 32
#define N_ 151
#define DIM_ 512
#define H_ 8
#define D_ 64
#define M_ (B_*N_)        // 4832
#define NPAD 160

typedef short bf16x8 __attribute__((ext_vector_type(8)));
typedef float f32x4  __attribute__((ext_vector_type(4)));

static __device__ __forceinline__ short f2bf(float f) {
  union { __hip_bfloat16 h; short s; } u;
  u.h = __float2bfloat16(f);
  return u.s;
}
// async global->LDS, 16B per lane; lds dest wave-uniform base (+lane*16 implicit)
static __device__ __forceinline__ void gload16(const void* g, void* l) {
  __builtin_amdgcn_global_load_lds(
      (const __attribute__((address_space(1))) unsigned int*)(uintptr_t)g,
      (__attribute__((address_space(3))) unsigned int*)(unsigned int)(uintptr_t)l,
      16, 0, 0);
}

// ---------------- fused prep: W transposes + PE tables + x cvt (1024 blocks) ----------------
__global__ __launch_bounds__(256) void prep_kernel(
    const float* __restrict__ x, const float* __restrict__ W_qkv,
    const float* __restrict__ W_out, const float* __restrict__ angle_enc,
    const float* __restrict__ cls_dist, const float* __restrict__ cls_angle,
    short* __restrict__ xb, short* __restrict__ wqT, short* __restrict__ woT,
    float* __restrict__ pe_k, float* __restrict__ pe_v)
{
  __shared__ float smf[32*33];
  const int bx = blockIdx.x;
  const int t = threadIdx.x;
  const int lx = t & 31, ly = t >> 5;

  // --- transpose section: blocks 0..767 -> W_qkv (512x1536); 768..1023 -> W_out (512x512)
  {
    const float* in; short* out; int R, C, tc, tr;
    if (bx < 768) { in = W_qkv; out = wqT; R = 512; C = 1536; tc = (bx % 48) * 32; tr = (bx / 48) * 32; }
    else          { in = W_out; out = woT; R = 512; C = 512;  tc = ((bx - 768) % 16) * 32; tr = ((bx - 768) / 16) * 32; }
    float (*tile)[33] = (float(*)[33])smf;
    #pragma unroll
    for (int dy = 0; dy < 32; dy += 8)
      tile[ly + dy][lx] = in[(tr + ly + dy) * C + tc + lx];
    __syncthreads();
    #pragma unroll
    for (int dy = 0; dy < 32; dy += 8)
      out[(tc + ly + dy) * R + tr + lx] = f2bf(tile[lx][ly + dy]);
  }
  __syncthreads();

  // --- freq table (32 values, f64 pow once per block)
  if (t < 32) smf[t] = (float)pow(10000.0, (double)t / 32.0);
  __syncthreads();

  // --- PE tables, grid-stride
  for (int idx = bx * 256 + t; idx < M_ * 64; idx += 1024 * 256) {
    int bn = idx >> 6, d = idx & 63;
    int b = bn / N_, n = bn - b * N_;
    float ek = (n == 0) ? cls_dist[0]  : angle_enc[b*(N_-1) + (n-1)];
    float ev = (n == 0) ? cls_angle[0] : angle_enc[b*(N_-1) + (n-1)];
    double freq = (double)smf[(d >> 1)];
    float pk = (float)floor(((double)ek * 151.0) / freq);
    float pv = (float)floor(((double)ev * 151.0) / freq);
    pe_k[idx] = (d & 1) ? cosf(pk) : sinf(pk);
    pe_v[idx] = (d & 1) ? cosf(pv) : sinf(pv);
  }

  // --- x -> bf16, grid-stride over float4s
  const int n4 = (M_ * DIM_) / 4;
  for (int i = bx * 256 + t; i < n4; i += 1024 * 256) {
    float4 v = ((const float4*)x)[i];
    short4 o;
    o.x = f2bf(v.x); o.y = f2bf(v.y); o.z = f2bf(v.z); o.w = f2bf(v.w);
    ((short4*)xb)[i] = o;
  }
}

// ---------------- bf16 MFMA GEMM, dbuf BK=64, XOR-swizzled LDS ----------------
// C(M x Nt) = A(M x 512) * Bt(Nt x 512)^T
// EPI 0: qkv epilogue (Q bf16; Kh = bf16(k+pe_k); Vt_g = bf16(v+pe_v) TRANSPOSED [bh][d][n160])
// EPI 1: out epilogue (+bias, f32 d_out)
template<int EPI, int BM, int BN_, int WM, int WN>
__global__ __launch_bounds__(256, 3) void gemm_kernel(
    const short* __restrict__ A, const short* __restrict__ Bt,
    const float* __restrict__ pe_k, const float* __restrict__ pe_v,
    short* __restrict__ Qb, short* __restrict__ Kh, short* __restrict__ Vtg,
    const float* __restrict__ bias, float* __restrict__ Out)
{
  constexpr int MI = BM / (WM * 16);
  constexpr int NI = BN_ / (WN * 16);
  constexpr int NT = DIM_ / 64;
  __shared__ short Ash[2][BM][64];
  __shared__ short Bsh[2][BN_][64];

  const int m0 = blockIdx.x * BM;
  const int n0 = blockIdx.y * BN_;
  const int t = threadIdx.x;
  const int wave = t >> 6, lane = t & 63;
  const int fr = lane & 15, fq = lane >> 4;
  const int wr = wave / WN, wc = wave % WN;
  const int srow = lane >> 3;                       // 0..7
  const int scol = ((lane & 7) ^ srow) << 3;        // pre-swizzled source col (shorts)

  const f32x4 zero = {0.f, 0.f, 0.f, 0.f};
  f32x4 acc[MI][NI];
  #pragma unroll
  for (int i = 0; i < MI; i++)
    #pragma unroll
    for (int j = 0; j < NI; j++) acc[i][j] = zero;

  auto stage = [&](int buf, int k0) {
    #pragma unroll
    for (int c = wave; c < BM/8; c += 4)
      gload16(A + (long)(m0 + c*8 + srow) * DIM_ + k0 + scol, &Ash[buf][c*8][0]);
    #pragma unroll
    for (int c = wave; c < BN_/8; c += 4)
      gload16(Bt + (long)(n0 + c*8 + srow) * DIM_ + k0 + scol, &Bsh[buf][c*8][0]);
  };

  stage(0, 0);
  asm volatile("s_waitcnt vmcnt(0)" ::: "memory");
  __syncthreads();

  int cur = 0;
  for (int it = 0; it < NT; ++it) {
    if (it + 1 < NT) stage(cur ^ 1, (it + 1) * 64);

    #pragma unroll
    for (int kk = 0; kk < 2; kk++) {
      const int rc = (kk*32 + fq*8) ^ ((fr & 7) << 3);   // swizzled read col (shorts)
      bf16x8 af[MI], bf[NI];
      #pragma unroll
      for (int mi = 0; mi < MI; mi++)
        af[mi] = *(const bf16x8*)(&Ash[cur][wr * (BM/WM) + mi*16 + fr][rc]);
      #pragma unroll
      for (int ni = 0; ni < NI; ni++)
        bf[ni] = *(const bf16x8*)(&Bsh[cur][wc * (BN_/WN) + ni*16 + fr][rc]);
      #pragma unroll
      for (int mi = 0; mi < MI; mi++)
        #pragma unroll
        for (int ni = 0; ni < NI; ni++)
          acc[mi][ni] = __builtin_amdgcn_mfma_f32_16x16x32_bf16(af[mi], bf[ni], acc[mi][ni], 0, 0, 0);
    }

    asm volatile("s_waitcnt vmcnt(0)" ::: "memory");
    __syncthreads();
    cur ^= 1;
  }

  #pragma unroll
  for (int mi = 0; mi < MI; mi++) {
    #pragma unroll
    for (int ni = 0; ni < NI; ni++) {
      #pragma unroll
      for (int r = 0; r < 4; r++) {
        int gm = m0 + wr * (BM/WM) + mi*16 + fq*4 + r;
        int gn = n0 + wc * (BN_/WN) + ni*16 + fr;
        if (gm >= M_) continue;
        float val = acc[mi][ni][r];
        if (EPI == 0) {
          int b = gm / N_, n = gm - b * N_;
          int sect = gn >> 9;                  // 0=q 1=k 2=v
          int h = (gn >> 6) & 7;
          int d = gn & 63;
          int bh = b*H_ + h;
          if (sect == 0) {
            Qb[(bh*N_ + n)*64 + d] = f2bf(val);
          } else if (sect == 1) {
            Kh[(bh*N_ + n)*64 + d] = f2bf(val + pe_k[gm*64 + d]);   // K' = k + pe_k
          } else {
            Vtg[((long)bh*64 + d)*160 + n] = f2bf(val + pe_v[gm*64 + d]); // V'^T
          }
        } else {
          Out[(long)gm*DIM_ + gn] = val + bias[gn];   // f32 output
        }
      }
    }
  }
}

// ---------------- fused attention: 1 wave per (bh, q-strip), no staging, no barriers ----------------
// K' and V'^T read directly from global (L2-resident, reused 10x per bh).
__global__ __launch_bounds__(64) void attn_kernel(
    const short* __restrict__ Qb, const short* __restrict__ Kh,
    const short* __restrict__ Vtg, const float* __restrict__ pe_v,
    short* __restrict__ Wh)
{
  __shared__ short Ps[16][NPAD + 8];       // per-block (1 wave) P strip, 5.4 KB

  const int bh = blockIdx.x;
  const int b = bh >> 3, h = bh & 7;
  const int s = blockIdx.y;                // q-strip 0..9
  const int lane = threadIdx.x;
  const int fr = lane & 15, fq = lane >> 4, fo = fq * 8;
  const int base = bh * (N_ * 64);
  const int q0 = s * 16;
  const f32x4 zero = {0.f, 0.f, 0.f, 0.f};

  // Q A-frags from global
  bf16x8 aq0 = {0,0,0,0,0,0,0,0}, aq1 = {0,0,0,0,0,0,0,0};
  if (q0 + fr < N_) {
    const short* qr = Qb + base + (q0 + fr) * 64;
    aq0 = *(const bf16x8*)(qr + fo);
    aq1 = *(const bf16x8*)(qr + 32 + fo);
  }
  // S = Q . K'  (B-frags straight from global; rows >= N_ masked below)
  f32x4 sf[10];
  #pragma unroll
  for (int kt = 0; kt < 10; kt++) {
    const short* kr = Kh + base + (kt*16 + fr) * 64;
    bf16x8 bh0 = *(const bf16x8*)(kr + fo);
    bf16x8 bh1 = *(const bf16x8*)(kr + 32 + fo);
    f32x4 s0 = __builtin_amdgcn_mfma_f32_16x16x32_bf16(aq0, bh0, zero, 0, 0, 0);
    sf[kt]   = __builtin_amdgcn_mfma_f32_16x16x32_bf16(aq1, bh1, s0, 0, 0, 0);
  }
  #pragma unroll
  for (int kt = 0; kt < 10; kt++) {
    int col = kt*16 + fr;
    #pragma unroll
    for (int r = 0; r < 4; r++) {
      float v = sf[kt][r] * 0.125f;
      sf[kt][r] = (col < N_) ? v : -1e30f;
    }
  }
  float mx[4], sum[4];
  #pragma unroll
  for (int r = 0; r < 4; r++) {
    float m = sf[0][r];
    #pragma unroll
    for (int kt = 1; kt < 10; kt++) m = fmaxf(m, sf[kt][r]);
    #pragma unroll
    for (int off = 1; off < 16; off <<= 1) m = fmaxf(m, __shfl_xor(m, off));
    mx[r] = m;
  }
  #pragma unroll
  for (int kt = 0; kt < 10; kt++)
    #pragma unroll
    for (int r = 0; r < 4; r++)
      sf[kt][r] = exp2f((sf[kt][r] - mx[r]) * 1.4426950408889634f);
  #pragma unroll
  for (int r = 0; r < 4; r++) {
    float sm = 0.f;
    #pragma unroll
    for (int kt = 0; kt < 10; kt++) sm += sf[kt][r];
    #pragma unroll
    for (int off = 1; off < 16; off <<= 1) sm += __shfl_xor(sm, off);
    sum[r] = sm;
  }
  // P -> LDS (wave-synchronous; compiler orders ds ops via lgkmcnt)
  #pragma unroll
  for (int kt = 0; kt < 10; kt++)
    #pragma unroll
    for (int r = 0; r < 4; r++)
      Ps[fq*4 + r][kt*16 + fr] = f2bf(sf[kt][r]);
  // O = P . V'  (V'^T B-frags straight from global)
  f32x4 o[4] = {zero, zero, zero, zero};
  #pragma unroll
  for (int kc = 0; kc < 5; kc++) {
    bf16x8 pa = *(const bf16x8*)(&Ps[fr][kc*32 + fo]);
    #pragma unroll
    for (int nb = 0; nb < 4; nb++) {
      bf16x8 bv = *(const bf16x8*)(Vtg + ((long)bh*64 + nb*16 + fr)*160 + kc*32 + fo);
      o[nb] = __builtin_amdgcn_mfma_f32_16x16x32_bf16(pa, bv, o[nb], 0, 0, 0);
    }
  }
  float inv[4];
  #pragma unroll
  for (int r = 0; r < 4; r++) inv[r] = 1.0f / sum[r];
  #pragma unroll
  for (int nb = 0; nb < 4; nb++) {
    #pragma unroll
    for (int r = 0; r < 4; r++) {
      int n = q0 + fq*4 + r;
      if (n < N_) {
        int d = nb*16 + fr;
        float val = o[nb][r] * inv[r] - pe_v[(b*N_ + n)*64 + d];
        Wh[(b*N_ + n)*DIM_ + h*64 + d] = f2bf(val);
      }
    }
  }
}

extern "C" void kernel_launch(void* const* d_in, const int* in_sizes, int n_in,
                              void* d_out, int out_size, void* d_ws, size_t ws_size,
                              hipStream_t stream) {
  const float* x         = (const float*)d_in[0];
  const float* angle_enc = (const float*)d_in[1];
  const float* W_qkv     = (const float*)d_in[2];
  const float* W_out     = (const float*)d_in[3];
  const float* b_out     = (const float*)d_in[4];
  const float* cls_dist  = (const float*)d_in[5];
  const float* cls_angle = (const float*)d_in[6];

  char* ws = (char*)d_ws;
  size_t off = 0;
  auto carve = [&](size_t bytes) { size_t o = off; off += (bytes + 255) & ~(size_t)255; return o; };
  const size_t MD2 = (size_t)M_ * DIM_ * 2;

  float* pe_k = (float*)(ws + carve((size_t)M_ * 64 * 4));
  float* pe_v = (float*)(ws + carve((size_t)M_ * 64 * 4));
  short* xb   = (short*)(ws + carve(MD2));
  short* wqT  = (short*)(ws + carve((size_t)1536 * 512 * 2));
  short* woT  = (short*)(ws + carve((size_t)512 * 512 * 2));
  short* Qb   = (short*)(ws + carve(MD2));
  short* Khb  = (short*)(ws + carve(MD2));
  short* Vtg  = (short*)(ws + carve((size_t)B_ * H_ * 64 * 160 * 2));
  short* Wh   = xb;   // xb dead after gemm<0>

  prep_kernel<<<1024, 256, 0, stream>>>(x, W_qkv, W_out, angle_enc, cls_dist, cls_angle,
                                        xb, wqT, woT, pe_k, pe_v);

  gemm_kernel<0, 64, 128, 1, 4><<<dim3((M_ + 63)/64, 1536/128), 256, 0, stream>>>(
      xb, wqT, pe_k, pe_v, Qb, Khb, Vtg, nullptr, nullptr);

  attn_kernel<<<dim3(B_ * H_, 10), 64, 0, stream>>>(Qb, Khb, Vtg, pe_v, Wh);

  gemm_kernel<1, 64, 64, 2, 2><<<dim3((M_ + 63)/64, DIM_/64), 256, 0, stream>>>(
      Wh, woT, nullptr, nullptr, nullptr, nullptr, nullptr,
      b_out, (float*)d_out);
}